// Round 3
// baseline (213.856 us; speedup 1.0000x reference)
//
#include <hip/hip_runtime.h>

typedef __attribute__((ext_vector_type(8))) short bh8;   // 8 x bf16 (16B)
typedef __attribute__((ext_vector_type(4))) float f4;

static __device__ __forceinline__ float b2f(unsigned short u){
  union { unsigned int i; float f; } c; c.i = ((unsigned int)u) << 16; return c.f;
}
static __device__ __forceinline__ unsigned short f2b(float f){
  union { float f; unsigned int i; } c; c.f = f;
  unsigned int u = c.i; u += 0x7fffu + ((u >> 16) & 1u);
  return (unsigned short)(u >> 16);
}
static __device__ __forceinline__ float elu1(float x){ return x > 0.f ? x : (__expf(x) - 1.f); }
static __device__ __forceinline__ float lrelu(float x){ return x > 0.f ? x : 0.2f * x; }
static __device__ __forceinline__ float gload(const void* p, size_t i, int isf32){
  return isf32 ? ((const float*)p)[i] : b2f(((const unsigned short*)p)[i]);
}
// per-wave dtype vote: sample 64 words of W0; bf16 -> low u16 is a plausible small
// bf16 (exp 100..126) ~64/64; fp32 -> low u16 is mantissa noise (~10%).
static __device__ __forceinline__ int detect_f32(const unsigned int* __restrict__ W0w, int lane){
  unsigned int w = W0w[lane & 63];
  unsigned int e = (w >> 7) & 0xFFu;
  unsigned long long m = __ballot(e >= 100u && e <= 126u);
  return (__popcll(m) < 32) ? 1 : 0;
}

// ---------------- prep: bf16 transposed + augmented weight tables ----------------
__global__ __launch_bounds__(256) void prep_kernel(
    const void* __restrict__ W0, const void* __restrict__ a0,
    const void* __restrict__ W1, const void* __restrict__ a1,
    unsigned short* __restrict__ Wt1, unsigned short* __restrict__ Wt2){
  int isf = detect_f32((const unsigned int*)W0, threadIdx.x & 63);
  int c = blockIdx.x, k = threadIdx.x;
  if (c < 272){
    float v;
    if (c < 256){
      int h = c >> 5, d = c & 31;
      v = gload(W0, (size_t)(h*256 + k)*32 + d, isf);
    } else if (c < 264){
      int h = c - 256; float s = 0.f;
      for (int d = 0; d < 32; d++)
        s += gload(W0, (size_t)(h*256 + k)*32 + d, isf) * gload(a0, h*64 + d, isf);
      v = s;
    } else {
      int h = c - 264; float s = 0.f;
      for (int d = 0; d < 32; d++)
        s += gload(W0, (size_t)(h*256 + k)*32 + d, isf) * gload(a0, h*64 + 32 + d, isf);
      v = s;
    }
    Wt1[c*256 + k] = f2b(v);
  } else {
    int c2 = c - 272; float v;
    if (c2 < 64) v = gload(W1, k*64 + c2, isf);
    else if (c2 == 64){ float s = 0.f; for (int i = 0; i < 64; i++) s += gload(W1, k*64+i, isf) * gload(a1, i, isf);      v = s; }
    else if (c2 == 65){ float s = 0.f; for (int i = 0; i < 64; i++) s += gload(W1, k*64+i, isf) * gload(a1, 64 + i, isf); v = s; }
    else v = 0.f;
    Wt2[c2*256 + k] = f2b(v);
  }
}

// ---------------- GEMM1 v5: barrier-free K-outer loop, full acc residency -------
__global__ __launch_bounds__(256, 3) void gemm1_mfma(
    const void* __restrict__ Xraw, const unsigned short* __restrict__ Wt,
    unsigned short* __restrict__ H1, float* __restrict__ S1, int N,
    const void* __restrict__ W0){
  __shared__ __align__(16) unsigned short A[80*264];
  int tid = threadIdx.x, wv = tid >> 6, lane = tid & 63;
  int isf = detect_f32((const unsigned int*)W0, lane);
  int q = lane >> 4, l = lane & 15;
  int n0 = blockIdx.x*80;
  #pragma unroll
  for (int it = 0; it < 10; it++){
    int g = it*256 + tid;
    int r = g >> 5, c = g & 31;
    int grow = n0 + r; if (grow > N-1) grow = N-1;
    bh8 v;
    if (isf){
      const float* xr = (const float*)Xraw + (size_t)grow*256 + c*8;
      float4 u0 = *(const float4*)xr, u1 = *(const float4*)(xr + 4);
      v[0]=(short)f2b(u0.x); v[1]=(short)f2b(u0.y); v[2]=(short)f2b(u0.z); v[3]=(short)f2b(u0.w);
      v[4]=(short)f2b(u1.x); v[5]=(short)f2b(u1.y); v[6]=(short)f2b(u1.z); v[7]=(short)f2b(u1.w);
    } else {
      v = *(const bh8*)((const unsigned short*)Xraw + (size_t)grow*256 + c*8);
    }
    *(bh8*)&A[r*264 + c*8] = v;
  }
  __syncthreads();
  const bh8* Wb = (const bh8*)Wt;
  f4 acc[5][4];
  f4 accS[5];
  f4 z = {0.f,0.f,0.f,0.f};
  #pragma unroll
  for (int m = 0; m < 5; m++){
    accS[m] = z;
    #pragma unroll
    for (int tt = 0; tt < 4; tt++) acc[m][tt] = z;
  }
  #pragma unroll
  for (int kk = 0; kk < 8; kk++){
    bh8 B0 = Wb[(size_t)((wv*4+0)*16 + l)*32 + kk*4 + q];
    bh8 B1 = Wb[(size_t)((wv*4+1)*16 + l)*32 + kk*4 + q];
    bh8 B2 = Wb[(size_t)((wv*4+2)*16 + l)*32 + kk*4 + q];
    bh8 B3 = Wb[(size_t)((wv*4+3)*16 + l)*32 + kk*4 + q];
    bh8 Bs;
    if (wv == 0) Bs = Wb[(size_t)(256 + l)*32 + kk*4 + q];
    #pragma unroll
    for (int m = 0; m < 5; m++){
      bh8 a = *(const bh8*)&A[(m*16 + l)*264 + kk*32 + q*8];
      acc[m][0] = __builtin_amdgcn_mfma_f32_16x16x32_bf16(a, B0, acc[m][0], 0, 0, 0);
      acc[m][1] = __builtin_amdgcn_mfma_f32_16x16x32_bf16(a, B1, acc[m][1], 0, 0, 0);
      acc[m][2] = __builtin_amdgcn_mfma_f32_16x16x32_bf16(a, B2, acc[m][2], 0, 0, 0);
      acc[m][3] = __builtin_amdgcn_mfma_f32_16x16x32_bf16(a, B3, acc[m][3], 0, 0, 0);
      if (wv == 0)
        accS[m] = __builtin_amdgcn_mfma_f32_16x16x32_bf16(a, Bs, accS[m], 0, 0, 0);
    }
  }
  __syncthreads();
  unsigned short* cs = &A[wv*1152];
  #pragma unroll
  for (int m = 0; m < 5; m++){
    #pragma unroll
    for (int tt = 0; tt < 4; tt++)
      #pragma unroll
      for (int r = 0; r < 4; r++)
        cs[(q*4 + r)*72 + tt*16 + l] = f2b(acc[m][tt][r]);
    if (wv == 0){
      #pragma unroll
      for (int r = 0; r < 4; r++){
        int row = n0 + m*16 + q*4 + r;
        if (row < N) S1[(size_t)row*16 + l] = accS[m][r];
      }
    }
    #pragma unroll
    for (int it2 = 0; it2 < 2; it2++){
      int r2 = lane & 15, ch = (lane >> 4) + it2*4;
      int row = n0 + m*16 + r2;
      if (row < N)
        *(bh8*)(H1 + (size_t)row*256 + wv*64 + ch*8) = *(const bh8*)&cs[r2*72 + ch*8];
    }
  }
}

// ---------------- FUSED agg1 + gemm2 v5: sched_barrier-pinned gather pipeline ----
// All 16 H1 gathers (np0) + all S1 loads issued, then sched_barrier(0) pins them
// in flight (64 landing VGPRs) while pure-VALU softmax runs. Same for np1.
__global__ __launch_bounds__(256, 3) void fused_agg1_gemm2(
    const float* __restrict__ S1, const unsigned short* __restrict__ H1,
    const int* __restrict__ dst, const unsigned short* __restrict__ Wt2,
    unsigned short* __restrict__ H2, float* __restrict__ S2, int N){
  __shared__ __align__(16) unsigned short Xt[16*264];
  __shared__ __align__(16) unsigned short Hs[16*88];
  int tid = threadIdx.x, wv = tid >> 6, lane = tid & 63;
  int n0 = blockIdx.x*16;
  int h = lane >> 3, jj = lane & 7;
  int half = lane >> 5, li = lane & 31;
  int cb = li*8, hc = li >> 2;

  int nA0 = n0 + wv*4 + 0; if (nA0 > N-1) nA0 = N-1;
  int nB0 = n0 + wv*4 + 1; if (nB0 > N-1) nB0 = N-1;
  int nA1 = n0 + wv*4 + 2; if (nA1 > N-1) nA1 = N-1;
  int nB1 = n0 + wv*4 + 3; if (nB1 > N-1) nB1 = N-1;
  const int* dA0p = dst + (size_t)nA0*16;
  const int* dB0p = dst + (size_t)nB0*16;
  const int* dA1p = dst + (size_t)nA1*16;
  const int* dB1p = dst + (size_t)nB1*16;

  // gather-row indices np0 (uniform per half — depth-1 address path)
  int rA0[8], rB0[8];
  #pragma unroll
  for (int i = 0; i < 8; i++){
    rA0[i] = dA0p[i*2 + half];
    rB0[i] = dB0p[i*2 + half];
  }
  // per-lane indices for softmax (all 4 nodes)
  int d0A0 = dA0p[jj], d1A0 = dA0p[jj + 8];
  int d0B0 = dB0p[jj], d1B0 = dB0p[jj + 8];
  int d0A1 = dA1p[jj], d1A1 = dA1p[jj + 8];
  int d0B1 = dB1p[jj], d1B1 = dB1p[jj + 8];

  // ---- issue: 16 H1 gathers np0 + all S1 loads ----
  bh8 bufA[8], bufB[8];
  #pragma unroll
  for (int i = 0; i < 8; i++){
    bufA[i] = *(const bh8*)(H1 + (size_t)rA0[i]*256 + cb);
    bufB[i] = *(const bh8*)(H1 + (size_t)rB0[i]*256 + cb);
  }
  float ssA0 = S1[(size_t)nA0*16 + h], ssB0 = S1[(size_t)nB0*16 + h];
  float ssA1 = S1[(size_t)nA1*16 + h], ssB1 = S1[(size_t)nB1*16 + h];
  float t0A0 = S1[(size_t)d0A0*16 + 8 + h], t1A0 = S1[(size_t)d1A0*16 + 8 + h];
  float t0B0 = S1[(size_t)d0B0*16 + 8 + h], t1B0 = S1[(size_t)d1B0*16 + 8 + h];
  float t0A1 = S1[(size_t)d0A1*16 + 8 + h], t1A1 = S1[(size_t)d1A1*16 + 8 + h];
  float t0B1 = S1[(size_t)d0B1*16 + 8 + h], t1B1 = S1[(size_t)d1B1*16 + 8 + h];
  __builtin_amdgcn_sched_barrier(0);   // pin all loads above in flight

  // ---- pure-VALU softmax (runs under gather latency) ----
  float e0A0 = lrelu(ssA0 + t0A0), e1A0 = lrelu(ssA0 + t1A0);
  float e0B0 = lrelu(ssB0 + t0B0), e1B0 = lrelu(ssB0 + t1B0);
  float e0A1 = lrelu(ssA1 + t0A1), e1A1 = lrelu(ssA1 + t1A1);
  float e0B1 = lrelu(ssB1 + t0B1), e1B1 = lrelu(ssB1 + t1B1);

  float mA0 = fmaxf(e0A0, e1A0), mB0 = fmaxf(e0B0, e1B0);
  float mA1 = fmaxf(e0A1, e1A1), mB1 = fmaxf(e0B1, e1B1);
  mA0 = fmaxf(mA0, __shfl_xor(mA0, 1)); mB0 = fmaxf(mB0, __shfl_xor(mB0, 1));
  mA1 = fmaxf(mA1, __shfl_xor(mA1, 1)); mB1 = fmaxf(mB1, __shfl_xor(mB1, 1));
  mA0 = fmaxf(mA0, __shfl_xor(mA0, 2)); mB0 = fmaxf(mB0, __shfl_xor(mB0, 2));
  mA1 = fmaxf(mA1, __shfl_xor(mA1, 2)); mB1 = fmaxf(mB1, __shfl_xor(mB1, 2));
  mA0 = fmaxf(mA0, __shfl_xor(mA0, 4)); mB0 = fmaxf(mB0, __shfl_xor(mB0, 4));
  mA1 = fmaxf(mA1, __shfl_xor(mA1, 4)); mB1 = fmaxf(mB1, __shfl_xor(mB1, 4));
  float p0A0 = __expf(e0A0 - mA0), p1A0 = __expf(e1A0 - mA0);
  float p0B0 = __expf(e0B0 - mB0), p1B0 = __expf(e1B0 - mB0);
  float p0A1 = __expf(e0A1 - mA1), p1A1 = __expf(e1A1 - mA1);
  float p0B1 = __expf(e0B1 - mB1), p1B1 = __expf(e1B1 - mB1);
  float sA0 = p0A0 + p1A0, sB0 = p0B0 + p1B0;
  float sA1 = p0A1 + p1A1, sB1 = p0B1 + p1B1;
  sA0 += __shfl_xor(sA0, 1); sB0 += __shfl_xor(sB0, 1);
  sA1 += __shfl_xor(sA1, 1); sB1 += __shfl_xor(sB1, 1);
  sA0 += __shfl_xor(sA0, 2); sB0 += __shfl_xor(sB0, 2);
  sA1 += __shfl_xor(sA1, 2); sB1 += __shfl_xor(sB1, 2);
  sA0 += __shfl_xor(sA0, 4); sB0 += __shfl_xor(sB0, 4);
  sA1 += __shfl_xor(sA1, 4); sB1 += __shfl_xor(sB1, 4);
  float w0A0 = p0A0 / sA0, w1A0 = p1A0 / sA0;
  float w0B0 = p0B0 / sB0, w1B0 = p1B0 / sB0;
  float w0A1 = p0A1 / sA1, w1A1 = p1A1 / sA1;
  float w0B1 = p0B1 / sB1, w1B1 = p1B1 / sB1;

  int rA1[8], rB1[8];
  #pragma unroll
  for (int i = 0; i < 8; i++){
    rA1[i] = dA1p[i*2 + half];
    rB1[i] = dB1p[i*2 + half];
  }

  // ---- consume np0 ----
  float accA[8] = {0.f,0.f,0.f,0.f,0.f,0.f,0.f,0.f};
  float accB[8] = {0.f,0.f,0.f,0.f,0.f,0.f,0.f,0.f};
  #pragma unroll
  for (int i = 0; i < 8; i++){
    int jl = (i*2 + half) & 7;
    float awA = (i < 4) ? __shfl(w0A0, hc*8 + jl) : __shfl(w1A0, hc*8 + jl);
    float awB = (i < 4) ? __shfl(w0B0, hc*8 + jl) : __shfl(w1B0, hc*8 + jl);
    #pragma unroll
    for (int c = 0; c < 8; c++){
      accA[c] += awA * b2f((unsigned short)bufA[i][c]);
      accB[c] += awB * b2f((unsigned short)bufB[i][c]);
    }
  }

  // ---- issue np1 gathers, pin ----
  bh8 buf2A[8], buf2B[8];
  #pragma unroll
  for (int i = 0; i < 8; i++){
    buf2A[i] = *(const bh8*)(H1 + (size_t)rA1[i]*256 + cb);
    buf2B[i] = *(const bh8*)(H1 + (size_t)rB1[i]*256 + cb);
  }
  __builtin_amdgcn_sched_barrier(0);   // pin np1 gathers in flight

  // ---- reduce + write Xt np0 (overlaps np1 latency) ----
  #pragma unroll
  for (int c = 0; c < 8; c++){
    accA[c] += __shfl_xor(accA[c], 32);
    accB[c] += __shfl_xor(accB[c], 32);
  }
  if (half == 0){
    bh8 oA, oB;
    #pragma unroll
    for (int c = 0; c < 8; c++){
      oA[c] = (short)f2b(elu1(accA[c]));
      oB[c] = (short)f2b(elu1(accB[c]));
    }
    *(bh8*)&Xt[(wv*4 + 0)*264 + cb] = oA;
    *(bh8*)&Xt[(wv*4 + 1)*264 + cb] = oB;
  }

  // ---- consume np1 ----
  float acA[8] = {0.f,0.f,0.f,0.f,0.f,0.f,0.f,0.f};
  float acB[8] = {0.f,0.f,0.f,0.f,0.f,0.f,0.f,0.f};
  #pragma unroll
  for (int i = 0; i < 8; i++){
    int jl = (i*2 + half) & 7;
    float awA = (i < 4) ? __shfl(w0A1, hc*8 + jl) : __shfl(w1A1, hc*8 + jl);
    float awB = (i < 4) ? __shfl(w0B1, hc*8 + jl) : __shfl(w1B1, hc*8 + jl);
    #pragma unroll
    for (int c = 0; c < 8; c++){
      acA[c] += awA * b2f((unsigned short)buf2A[i][c]);
      acB[c] += awB * b2f((unsigned short)buf2B[i][c]);
    }
  }
  #pragma unroll
  for (int c = 0; c < 8; c++){
    acA[c] += __shfl_xor(acA[c], 32);
    acB[c] += __shfl_xor(acB[c], 32);
  }
  if (half == 0){
    bh8 oA, oB;
    #pragma unroll
    for (int c = 0; c < 8; c++){
      oA[c] = (short)f2b(elu1(acA[c]));
      oB[c] = (short)f2b(elu1(acB[c]));
    }
    *(bh8*)&Xt[(wv*4 + 2)*264 + cb] = oA;
    *(bh8*)&Xt[(wv*4 + 3)*264 + cb] = oB;
  }
  __syncthreads();

  // ---- phase B: 16-row GEMM2 (unchanged) ----
  {
    int q = lane >> 4, l = lane & 15;
    bh8 a[8];
    #pragma unroll
    for (int kk = 0; kk < 8; kk++)
      a[kk] = *(const bh8*)&Xt[l*264 + kk*32 + q*8];
    const bh8* Wb = (const bh8*)Wt2;
    int ntt = (wv == 3) ? 2 : 1;
    for (int it = 0; it < ntt; it++){
      int tt = (it == 0) ? wv : 4;
      bh8 b[8];
      #pragma unroll
      for (int kk = 0; kk < 8; kk++) b[kk] = Wb[(size_t)(tt*16 + l)*32 + kk*4 + q];
      f4 c0 = {0.f,0.f,0.f,0.f};
      #pragma unroll
      for (int kk = 0; kk < 8; kk++)
        c0 = __builtin_amdgcn_mfma_f32_16x16x32_bf16(a[kk], b[kk], c0, 0, 0, 0);
      if (tt < 4){
        #pragma unroll
        for (int r = 0; r < 4; r++)
          Hs[(q*4 + r)*88 + tt*16 + l] = f2b(c0[r]);
      } else if (l < 2){
        #pragma unroll
        for (int r = 0; r < 4; r++){
          int row0 = n0 + q*4 + r;
          if (row0 < N) S2[(size_t)row0*2 + l] = c0[r];
        }
      }
    }
  }
  __syncthreads();
  if (tid < 128){
    int r2 = tid >> 3, ch = tid & 7;
    int row = n0 + r2;
    if (row < N)
      *(bh8*)(H2 + (size_t)row*64 + ch*8) = *(const bh8*)&Hs[r2*88 + ch*8];
  }
}

// ---------------- agg2 v4: sched_barrier-pinned gathers ----------------
__global__ __launch_bounds__(256) void agg2_kernel(
    const float* __restrict__ S2, const unsigned short* __restrict__ H2,
    const int* __restrict__ dst, void* __restrict__ outv, int N,
    const void* __restrict__ W0){
  int tid = threadIdx.x, wv = tid >> 6, lane = tid & 63;
  int isf = detect_f32((const unsigned int*)W0, lane);
  int nodeA = blockIdx.x*8 + wv*2; if (nodeA > N-1) nodeA = N-1;
  int nodeB = nodeA + 1;           if (nodeB > N-1) nodeB = N-1;
  int g = lane >> 3, cbl = (lane & 7)*8;
  int rA0v = dst[(size_t)nodeA*16 + g];
  int rA1v = dst[(size_t)nodeA*16 + 8 + g];
  int rB0v = dst[(size_t)nodeB*16 + g];
  int rB1v = dst[(size_t)nodeB*16 + 8 + g];
  int j = lane & 15;
  int dA = dst[(size_t)nodeA*16 + j];
  int dB = dst[(size_t)nodeB*16 + j];
  // issue all gathers + score loads, pin in flight
  bh8 vA0 = *(const bh8*)(H2 + (size_t)rA0v*64 + cbl);
  bh8 vA1 = *(const bh8*)(H2 + (size_t)rA1v*64 + cbl);
  bh8 vB0 = *(const bh8*)(H2 + (size_t)rB0v*64 + cbl);
  bh8 vB1 = *(const bh8*)(H2 + (size_t)rB1v*64 + cbl);
  float s0A = S2[(size_t)nodeA*2], s0B = S2[(size_t)nodeB*2];
  float sdA = S2[(size_t)dA*2 + 1], sdB = S2[(size_t)dB*2 + 1];
  __builtin_amdgcn_sched_barrier(0);
  float eA = lrelu(s0A + sdA);
  float eB = lrelu(s0B + sdB);
  float mA = eA, mB = eB;
  mA = fmaxf(mA, __shfl_xor(mA, 1)); mB = fmaxf(mB, __shfl_xor(mB, 1));
  mA = fmaxf(mA, __shfl_xor(mA, 2)); mB = fmaxf(mB, __shfl_xor(mB, 2));
  mA = fmaxf(mA, __shfl_xor(mA, 4)); mB = fmaxf(mB, __shfl_xor(mB, 4));
  mA = fmaxf(mA, __shfl_xor(mA, 8)); mB = fmaxf(mB, __shfl_xor(mB, 8));
  float pA = __expf(eA - mA), pB = __expf(eB - mB);
  float sA = pA, sB = pB;
  sA += __shfl_xor(sA, 1); sB += __shfl_xor(sB, 1);
  sA += __shfl_xor(sA, 2); sB += __shfl_xor(sB, 2);
  sA += __shfl_xor(sA, 4); sB += __shfl_xor(sB, 4);
  sA += __shfl_xor(sA, 8); sB += __shfl_xor(sB, 8);
  float attA = pA / sA, attB = pB / sB;
  float awA0 = __shfl(attA, g),     awB0 = __shfl(attB, g);
  float awA1 = __shfl(attA, 8 + g), awB1 = __shfl(attB, 8 + g);
  float accA[8], accB[8];
  #pragma unroll
  for (int c = 0; c < 8; c++){
    accA[c] = awA0 * b2f((unsigned short)vA0[c]) + awA1 * b2f((unsigned short)vA1[c]);
    accB[c] = awB0 * b2f((unsigned short)vB0[c]) + awB1 * b2f((unsigned short)vB1[c]);
  }
  #pragma unroll
  for (int c = 0; c < 8; c++){
    accA[c] += __shfl_xor(accA[c], 8);  accB[c] += __shfl_xor(accB[c], 8);
    accA[c] += __shfl_xor(accA[c], 16); accB[c] += __shfl_xor(accB[c], 16);
    accA[c] += __shfl_xor(accA[c], 32); accB[c] += __shfl_xor(accB[c], 32);
  }
  if (lane < 8){
    size_t oiA = (size_t)nodeA*64 + cbl;
    size_t oiB = (size_t)nodeB*64 + cbl;
    if (isf){
      float4 a0v, a1v, b0v, b1v;
      a0v.x = elu1(accA[0]); a0v.y = elu1(accA[1]); a0v.z = elu1(accA[2]); a0v.w = elu1(accA[3]);
      a1v.x = elu1(accA[4]); a1v.y = elu1(accA[5]); a1v.z = elu1(accA[6]); a1v.w = elu1(accA[7]);
      b0v.x = elu1(accB[0]); b0v.y = elu1(accB[1]); b0v.z = elu1(accB[2]); b0v.w = elu1(accB[3]);
      b1v.x = elu1(accB[4]); b1v.y = elu1(accB[5]); b1v.z = elu1(accB[6]); b1v.w = elu1(accB[7]);
      *(float4*)((float*)outv + oiA)     = a0v;
      *(float4*)((float*)outv + oiA + 4) = a1v;
      *(float4*)((float*)outv + oiB)     = b0v;
      *(float4*)((float*)outv + oiB + 4) = b1v;
    } else {
      bh8 oA, oB;
      #pragma unroll
      for (int c = 0; c < 8; c++){
        oA[c] = (short)f2b(elu1(accA[c]));
        oB[c] = (short)f2b(elu1(accB[c]));
      }
      *(bh8*)((unsigned short*)outv + oiA) = oA;
      *(bh8*)((unsigned short*)outv + oiB) = oB;
    }
  }
}

extern "C" void kernel_launch(void* const* d_in, const int* in_sizes, int n_in,
                              void* d_out, int out_size, void* d_ws, size_t ws_size,
                              hipStream_t stream){
  const void* X  = d_in[0];
  const int*  ed = (const int*)d_in[1];
  const void* W0 = d_in[2];
  const void* a0 = d_in[3];
  const void* W1 = d_in[4];
  const void* a1 = d_in[5];

  int N = in_sizes[0] / 256;       // 50000
  int E = N * 16;
  const int* dst = ed + E;         // edges[1]; src is structurally e>>4

  char* w = (char*)d_ws;
  size_t off = 0;
  auto alloc = [&](size_t bytes) -> void* {
    void* p = w + off; off += (bytes + 255) & ~(size_t)255; return p;
  };
  unsigned short* Wt1 = (unsigned short*)alloc(272*256*2);
  unsigned short* Wt2 = (unsigned short*)alloc(80*256*2);
  float*          S1  = (float*)alloc((size_t)N*16*4);
  unsigned short* H1  = (unsigned short*)alloc((size_t)N*256*2);
  unsigned short* H2  = (unsigned short*)alloc((size_t)N*64*2);
  float*          S2  = (float*)alloc((size_t)N*2*4);
  (void)ws_size; (void)n_in; (void)out_size;

  int g1 = (N + 79) / 80;
  int gf = (N + 15) / 16;
  int ab = (N + 7) / 8;
  prep_kernel     <<<352,256, 0, stream>>>(W0, a0, W1, a1, Wt1, Wt2);
  gemm1_mfma      <<<g1, 256, 0, stream>>>(X,  Wt1, H1, S1, N, W0);
  fused_agg1_gemm2<<<gf, 256, 0, stream>>>(S1, H1, dst, Wt2, H2, S2, N);
  agg2_kernel     <<<ab, 256, 0, stream>>>(S2, H2, dst, d_out, N, W0);
}

// Round 4
// 211.259 us; speedup vs baseline: 1.0123x; 1.0123x over previous
//
#include <hip/hip_runtime.h>

typedef __attribute__((ext_vector_type(8))) short bh8;   // 8 x bf16 (16B)
typedef __attribute__((ext_vector_type(4))) float f4;

#define VMWAIT(N) asm volatile("s_waitcnt vmcnt(" #N ")" ::: "memory")

static __device__ __forceinline__ float b2f(unsigned short u){
  union { unsigned int i; float f; } c; c.i = ((unsigned int)u) << 16; return c.f;
}
static __device__ __forceinline__ unsigned short f2b(float f){
  union { float f; unsigned int i; } c; c.f = f;
  unsigned int u = c.i; u += 0x7fffu + ((u >> 16) & 1u);
  return (unsigned short)(u >> 16);
}
static __device__ __forceinline__ float elu1(float x){ return x > 0.f ? x : (__expf(x) - 1.f); }
static __device__ __forceinline__ float lrelu(float x){ return x > 0.f ? x : 0.2f * x; }
static __device__ __forceinline__ float gload(const void* p, size_t i, int isf32){
  return isf32 ? ((const float*)p)[i] : b2f(((const unsigned short*)p)[i]);
}
// forced-in-flight loads: SGPR base + 32-bit VGPR byte offset, volatile asm.
// Caller is responsible for s_waitcnt before consuming the result.
static __device__ __forceinline__ f4 gld16(const void* base, unsigned int voff){
  f4 r;
  asm volatile("global_load_dwordx4 %0, %1, %2"
               : "=v"(r) : "v"(voff), "s"(base) : "memory");
  return r;
}
static __device__ __forceinline__ float gld4(const void* base, unsigned int voff){
  float r;
  asm volatile("global_load_dword %0, %1, %2"
               : "=v"(r) : "v"(voff), "s"(base) : "memory");
  return r;
}
// per-wave dtype vote: sample 64 words of W0; bf16 -> low u16 is a plausible small
// bf16 (exp 100..126) ~64/64; fp32 -> low u16 is mantissa noise (~10%).
static __device__ __forceinline__ int detect_f32(const unsigned int* __restrict__ W0w, int lane){
  unsigned int w = W0w[lane & 63];
  unsigned int e = (w >> 7) & 0xFFu;
  unsigned long long m = __ballot(e >= 100u && e <= 126u);
  return (__popcll(m) < 32) ? 1 : 0;
}

// ---------------- prep: bf16 transposed + augmented weight tables ----------------
__global__ __launch_bounds__(256) void prep_kernel(
    const void* __restrict__ W0, const void* __restrict__ a0,
    const void* __restrict__ W1, const void* __restrict__ a1,
    unsigned short* __restrict__ Wt1, unsigned short* __restrict__ Wt2){
  int isf = detect_f32((const unsigned int*)W0, threadIdx.x & 63);
  int c = blockIdx.x, k = threadIdx.x;
  if (c < 272){
    float v;
    if (c < 256){
      int h = c >> 5, d = c & 31;
      v = gload(W0, (size_t)(h*256 + k)*32 + d, isf);
    } else if (c < 264){
      int h = c - 256; float s = 0.f;
      for (int d = 0; d < 32; d++)
        s += gload(W0, (size_t)(h*256 + k)*32 + d, isf) * gload(a0, h*64 + d, isf);
      v = s;
    } else {
      int h = c - 264; float s = 0.f;
      for (int d = 0; d < 32; d++)
        s += gload(W0, (size_t)(h*256 + k)*32 + d, isf) * gload(a0, h*64 + 32 + d, isf);
      v = s;
    }
    Wt1[c*256 + k] = f2b(v);
  } else {
    int c2 = c - 272; float v;
    if (c2 < 64) v = gload(W1, k*64 + c2, isf);
    else if (c2 == 64){ float s = 0.f; for (int i = 0; i < 64; i++) s += gload(W1, k*64+i, isf) * gload(a1, i, isf);      v = s; }
    else if (c2 == 65){ float s = 0.f; for (int i = 0; i < 64; i++) s += gload(W1, k*64+i, isf) * gload(a1, 64 + i, isf); v = s; }
    else v = 0.f;
    Wt2[c2*256 + k] = f2b(v);
  }
}

// ---------------- GEMM1 v5: barrier-free K-outer loop, full acc residency -------
__global__ __launch_bounds__(256, 3) void gemm1_mfma(
    const void* __restrict__ Xraw, const unsigned short* __restrict__ Wt,
    unsigned short* __restrict__ H1, float* __restrict__ S1, int N,
    const void* __restrict__ W0){
  __shared__ __align__(16) unsigned short A[80*264];
  int tid = threadIdx.x, wv = tid >> 6, lane = tid & 63;
  int isf = detect_f32((const unsigned int*)W0, lane);
  int q = lane >> 4, l = lane & 15;
  int n0 = blockIdx.x*80;
  #pragma unroll
  for (int it = 0; it < 10; it++){
    int g = it*256 + tid;
    int r = g >> 5, c = g & 31;
    int grow = n0 + r; if (grow > N-1) grow = N-1;
    bh8 v;
    if (isf){
      const float* xr = (const float*)Xraw + (size_t)grow*256 + c*8;
      float4 u0 = *(const float4*)xr, u1 = *(const float4*)(xr + 4);
      v[0]=(short)f2b(u0.x); v[1]=(short)f2b(u0.y); v[2]=(short)f2b(u0.z); v[3]=(short)f2b(u0.w);
      v[4]=(short)f2b(u1.x); v[5]=(short)f2b(u1.y); v[6]=(short)f2b(u1.z); v[7]=(short)f2b(u1.w);
    } else {
      v = *(const bh8*)((const unsigned short*)Xraw + (size_t)grow*256 + c*8);
    }
    *(bh8*)&A[r*264 + c*8] = v;
  }
  __syncthreads();
  const bh8* Wb = (const bh8*)Wt;
  f4 acc[5][4];
  f4 accS[5];
  f4 z = {0.f,0.f,0.f,0.f};
  #pragma unroll
  for (int m = 0; m < 5; m++){
    accS[m] = z;
    #pragma unroll
    for (int tt = 0; tt < 4; tt++) acc[m][tt] = z;
  }
  #pragma unroll
  for (int kk = 0; kk < 8; kk++){
    bh8 B0 = Wb[(size_t)((wv*4+0)*16 + l)*32 + kk*4 + q];
    bh8 B1 = Wb[(size_t)((wv*4+1)*16 + l)*32 + kk*4 + q];
    bh8 B2 = Wb[(size_t)((wv*4+2)*16 + l)*32 + kk*4 + q];
    bh8 B3 = Wb[(size_t)((wv*4+3)*16 + l)*32 + kk*4 + q];
    bh8 Bs;
    if (wv == 0) Bs = Wb[(size_t)(256 + l)*32 + kk*4 + q];
    #pragma unroll
    for (int m = 0; m < 5; m++){
      bh8 a = *(const bh8*)&A[(m*16 + l)*264 + kk*32 + q*8];
      acc[m][0] = __builtin_amdgcn_mfma_f32_16x16x32_bf16(a, B0, acc[m][0], 0, 0, 0);
      acc[m][1] = __builtin_amdgcn_mfma_f32_16x16x32_bf16(a, B1, acc[m][1], 0, 0, 0);
      acc[m][2] = __builtin_amdgcn_mfma_f32_16x16x32_bf16(a, B2, acc[m][2], 0, 0, 0);
      acc[m][3] = __builtin_amdgcn_mfma_f32_16x16x32_bf16(a, B3, acc[m][3], 0, 0, 0);
      if (wv == 0)
        accS[m] = __builtin_amdgcn_mfma_f32_16x16x32_bf16(a, Bs, accS[m], 0, 0, 0);
    }
  }
  __syncthreads();
  unsigned short* cs = &A[wv*1152];
  #pragma unroll
  for (int m = 0; m < 5; m++){
    #pragma unroll
    for (int tt = 0; tt < 4; tt++)
      #pragma unroll
      for (int r = 0; r < 4; r++)
        cs[(q*4 + r)*72 + tt*16 + l] = f2b(acc[m][tt][r]);
    if (wv == 0){
      #pragma unroll
      for (int r = 0; r < 4; r++){
        int row = n0 + m*16 + q*4 + r;
        if (row < N) S1[(size_t)row*16 + l] = accS[m][r];
      }
    }
    #pragma unroll
    for (int it2 = 0; it2 < 2; it2++){
      int r2 = lane & 15, ch = (lane >> 4) + it2*4;
      int row = n0 + m*16 + r2;
      if (row < N)
        *(bh8*)(H1 + (size_t)row*256 + wv*64 + ch*8) = *(const bh8*)&cs[r2*72 + ch*8];
    }
  }
}

// ---------------- FUSED agg1 + gemm2 v6: asm-forced gather pipeline ----------------
// Queue order (volatile asm, guaranteed): 12 S1 score loads -> 16 np0 H1 gathers.
// vmcnt(16): scores done, gathers in flight -> softmax overlaps latency.
// vmcnt(0): consume np0; issue np1 gathers; reduce/Xt-write overlap; vmcnt(0); np1.
__global__ __launch_bounds__(256, 3) void fused_agg1_gemm2(
    const float* __restrict__ S1, const unsigned short* __restrict__ H1,
    const int* __restrict__ dst, const unsigned short* __restrict__ Wt2,
    unsigned short* __restrict__ H2, float* __restrict__ S2, int N){
  __shared__ __align__(16) unsigned short Xt[16*264];
  __shared__ __align__(16) unsigned short Hs[16*88];
  int tid = threadIdx.x, wv = tid >> 6, lane = tid & 63;
  int n0 = blockIdx.x*16;
  int h = lane >> 3, jj = lane & 7;
  int half = lane >> 5, li = lane & 31;
  int cb = li*8, hc = li >> 2;

  int nA0 = n0 + wv*4 + 0; if (nA0 > N-1) nA0 = N-1;
  int nB0 = n0 + wv*4 + 1; if (nB0 > N-1) nB0 = N-1;
  int nA1 = n0 + wv*4 + 2; if (nA1 > N-1) nA1 = N-1;
  int nB1 = n0 + wv*4 + 3; if (nB1 > N-1) nB1 = N-1;
  const int* dA0p = dst + (size_t)nA0*16;
  const int* dB0p = dst + (size_t)nB0*16;
  const int* dA1p = dst + (size_t)nA1*16;
  const int* dB1p = dst + (size_t)nB1*16;

  // all edge indices via normal loads (drained before asm region starts)
  int rA0[8], rB0[8], rA1[8], rB1[8];
  #pragma unroll
  for (int i = 0; i < 8; i++){
    rA0[i] = dA0p[i*2 + half];
    rB0[i] = dB0p[i*2 + half];
    rA1[i] = dA1p[i*2 + half];
    rB1[i] = dB1p[i*2 + half];
  }
  int d0A0 = dA0p[jj], d1A0 = dA0p[jj + 8];
  int d0B0 = dB0p[jj], d1B0 = dB0p[jj + 8];
  int d0A1 = dA1p[jj], d1A1 = dA1p[jj + 8];
  int d0B1 = dB1p[jj], d1B1 = dB1p[jj + 8];

  // ---- asm queue: 12 S1 score loads ----
  float ssA0 = gld4(S1, (unsigned)((nA0*16 + h)*4));
  float ssB0 = gld4(S1, (unsigned)((nB0*16 + h)*4));
  float ssA1 = gld4(S1, (unsigned)((nA1*16 + h)*4));
  float ssB1 = gld4(S1, (unsigned)((nB1*16 + h)*4));
  float t0A0 = gld4(S1, (unsigned)((d0A0*16 + 8 + h)*4));
  float t1A0 = gld4(S1, (unsigned)((d1A0*16 + 8 + h)*4));
  float t0B0 = gld4(S1, (unsigned)((d0B0*16 + 8 + h)*4));
  float t1B0 = gld4(S1, (unsigned)((d1B0*16 + 8 + h)*4));
  float t0A1 = gld4(S1, (unsigned)((d0A1*16 + 8 + h)*4));
  float t1A1 = gld4(S1, (unsigned)((d1A1*16 + 8 + h)*4));
  float t0B1 = gld4(S1, (unsigned)((d0B1*16 + 8 + h)*4));
  float t1B1 = gld4(S1, (unsigned)((d1B1*16 + 8 + h)*4));

  // ---- asm queue: 16 np0 H1 gathers (stay in flight through softmax) ----
  f4 bufA[8], bufB[8];
  #pragma unroll
  for (int i = 0; i < 8; i++){
    bufA[i] = gld16(H1, (unsigned)(rA0[i]*512 + cb*2));
    bufB[i] = gld16(H1, (unsigned)(rB0[i]*512 + cb*2));
  }

  VMWAIT(16);                          // S1 done (in-order), 16 gathers flying
  __builtin_amdgcn_sched_barrier(0);

  // ---- pure-VALU/shfl softmax under gather latency ----
  float e0A0 = lrelu(ssA0 + t0A0), e1A0 = lrelu(ssA0 + t1A0);
  float e0B0 = lrelu(ssB0 + t0B0), e1B0 = lrelu(ssB0 + t1B0);
  float e0A1 = lrelu(ssA1 + t0A1), e1A1 = lrelu(ssA1 + t1A1);
  float e0B1 = lrelu(ssB1 + t0B1), e1B1 = lrelu(ssB1 + t1B1);

  float mA0 = fmaxf(e0A0, e1A0), mB0 = fmaxf(e0B0, e1B0);
  float mA1 = fmaxf(e0A1, e1A1), mB1 = fmaxf(e0B1, e1B1);
  mA0 = fmaxf(mA0, __shfl_xor(mA0, 1)); mB0 = fmaxf(mB0, __shfl_xor(mB0, 1));
  mA1 = fmaxf(mA1, __shfl_xor(mA1, 1)); mB1 = fmaxf(mB1, __shfl_xor(mB1, 1));
  mA0 = fmaxf(mA0, __shfl_xor(mA0, 2)); mB0 = fmaxf(mB0, __shfl_xor(mB0, 2));
  mA1 = fmaxf(mA1, __shfl_xor(mA1, 2)); mB1 = fmaxf(mB1, __shfl_xor(mB1, 2));
  mA0 = fmaxf(mA0, __shfl_xor(mA0, 4)); mB0 = fmaxf(mB0, __shfl_xor(mB0, 4));
  mA1 = fmaxf(mA1, __shfl_xor(mA1, 4)); mB1 = fmaxf(mB1, __shfl_xor(mB1, 4));
  float p0A0 = __expf(e0A0 - mA0), p1A0 = __expf(e1A0 - mA0);
  float p0B0 = __expf(e0B0 - mB0), p1B0 = __expf(e1B0 - mB0);
  float p0A1 = __expf(e0A1 - mA1), p1A1 = __expf(e1A1 - mA1);
  float p0B1 = __expf(e0B1 - mB1), p1B1 = __expf(e1B1 - mB1);
  float sA0 = p0A0 + p1A0, sB0 = p0B0 + p1B0;
  float sA1 = p0A1 + p1A1, sB1 = p0B1 + p1B1;
  sA0 += __shfl_xor(sA0, 1); sB0 += __shfl_xor(sB0, 1);
  sA1 += __shfl_xor(sA1, 1); sB1 += __shfl_xor(sB1, 1);
  sA0 += __shfl_xor(sA0, 2); sB0 += __shfl_xor(sB0, 2);
  sA1 += __shfl_xor(sA1, 2); sB1 += __shfl_xor(sB1, 2);
  sA0 += __shfl_xor(sA0, 4); sB0 += __shfl_xor(sB0, 4);
  sA1 += __shfl_xor(sA1, 4); sB1 += __shfl_xor(sB1, 4);
  float w0A0 = p0A0 / sA0, w1A0 = p1A0 / sA0;
  float w0B0 = p0B0 / sB0, w1B0 = p1B0 / sB0;
  float w0A1 = p0A1 / sA1, w1A1 = p1A1 / sA1;
  float w0B1 = p0B1 / sB1, w1B1 = p1B1 / sB1;

  VMWAIT(0);                           // np0 gathers landed
  __builtin_amdgcn_sched_barrier(0);

  // ---- consume np0 ----
  float accA[8] = {0.f,0.f,0.f,0.f,0.f,0.f,0.f,0.f};
  float accB[8] = {0.f,0.f,0.f,0.f,0.f,0.f,0.f,0.f};
  #pragma unroll
  for (int i = 0; i < 8; i++){
    int jl = (i*2 + half) & 7;
    float awA = (i < 4) ? __shfl(w0A0, hc*8 + jl) : __shfl(w1A0, hc*8 + jl);
    float awB = (i < 4) ? __shfl(w0B0, hc*8 + jl) : __shfl(w1B0, hc*8 + jl);
    bh8 vA = __builtin_bit_cast(bh8, bufA[i]);
    bh8 vB = __builtin_bit_cast(bh8, bufB[i]);
    #pragma unroll
    for (int c = 0; c < 8; c++){
      accA[c] += awA * b2f((unsigned short)vA[c]);
      accB[c] += awB * b2f((unsigned short)vB[c]);
    }
  }

  // ---- issue np1 gathers (asm; fly over np0 epilogue) ----
  f4 buf2A[8], buf2B[8];
  #pragma unroll
  for (int i = 0; i < 8; i++){
    buf2A[i] = gld16(H1, (unsigned)(rA1[i]*512 + cb*2));
    buf2B[i] = gld16(H1, (unsigned)(rB1[i]*512 + cb*2));
  }

  // ---- reduce + write Xt np0 (overlaps np1 latency) ----
  #pragma unroll
  for (int c = 0; c < 8; c++){
    accA[c] += __shfl_xor(accA[c], 32);
    accB[c] += __shfl_xor(accB[c], 32);
  }
  if (half == 0){
    bh8 oA, oB;
    #pragma unroll
    for (int c = 0; c < 8; c++){
      oA[c] = (short)f2b(elu1(accA[c]));
      oB[c] = (short)f2b(elu1(accB[c]));
    }
    *(bh8*)&Xt[(wv*4 + 0)*264 + cb] = oA;
    *(bh8*)&Xt[(wv*4 + 1)*264 + cb] = oB;
  }

  VMWAIT(0);                           // np1 landed
  __builtin_amdgcn_sched_barrier(0);

  // ---- consume np1 ----
  float acA[8] = {0.f,0.f,0.f,0.f,0.f,0.f,0.f,0.f};
  float acB[8] = {0.f,0.f,0.f,0.f,0.f,0.f,0.f,0.f};
  #pragma unroll
  for (int i = 0; i < 8; i++){
    int jl = (i*2 + half) & 7;
    float awA = (i < 4) ? __shfl(w0A1, hc*8 + jl) : __shfl(w1A1, hc*8 + jl);
    float awB = (i < 4) ? __shfl(w0B1, hc*8 + jl) : __shfl(w1B1, hc*8 + jl);
    bh8 vA = __builtin_bit_cast(bh8, buf2A[i]);
    bh8 vB = __builtin_bit_cast(bh8, buf2B[i]);
    #pragma unroll
    for (int c = 0; c < 8; c++){
      acA[c] += awA * b2f((unsigned short)vA[c]);
      acB[c] += awB * b2f((unsigned short)vB[c]);
    }
  }
  #pragma unroll
  for (int c = 0; c < 8; c++){
    acA[c] += __shfl_xor(acA[c], 32);
    acB[c] += __shfl_xor(acB[c], 32);
  }
  if (half == 0){
    bh8 oA, oB;
    #pragma unroll
    for (int c = 0; c < 8; c++){
      oA[c] = (short)f2b(elu1(acA[c]));
      oB[c] = (short)f2b(elu1(acB[c]));
    }
    *(bh8*)&Xt[(wv*4 + 2)*264 + cb] = oA;
    *(bh8*)&Xt[(wv*4 + 3)*264 + cb] = oB;
  }
  __syncthreads();

  // ---- phase B: 16-row GEMM2 (unchanged) ----
  {
    int q = lane >> 4, l = lane & 15;
    bh8 a[8];
    #pragma unroll
    for (int kk = 0; kk < 8; kk++)
      a[kk] = *(const bh8*)&Xt[l*264 + kk*32 + q*8];
    const bh8* Wb = (const bh8*)Wt2;
    int ntt = (wv == 3) ? 2 : 1;
    for (int it = 0; it < ntt; it++){
      int tt = (it == 0) ? wv : 4;
      bh8 b[8];
      #pragma unroll
      for (int kk = 0; kk < 8; kk++) b[kk] = Wb[(size_t)(tt*16 + l)*32 + kk*4 + q];
      f4 c0 = {0.f,0.f,0.f,0.f};
      #pragma unroll
      for (int kk = 0; kk < 8; kk++)
        c0 = __builtin_amdgcn_mfma_f32_16x16x32_bf16(a[kk], b[kk], c0, 0, 0, 0);
      if (tt < 4){
        #pragma unroll
        for (int r = 0; r < 4; r++)
          Hs[(q*4 + r)*88 + tt*16 + l] = f2b(c0[r]);
      } else if (l < 2){
        #pragma unroll
        for (int r = 0; r < 4; r++){
          int row0 = n0 + q*4 + r;
          if (row0 < N) S2[(size_t)row0*2 + l] = c0[r];
        }
      }
    }
  }
  __syncthreads();
  if (tid < 128){
    int r2 = tid >> 3, ch = tid & 7;
    int row = n0 + r2;
    if (row < N)
      *(bh8*)(H2 + (size_t)row*64 + ch*8) = *(const bh8*)&Hs[r2*88 + ch*8];
  }
}

// ---------------- agg2 v5: asm-forced gathers + counted waits ----------------
__global__ __launch_bounds__(256) void agg2_kernel(
    const float* __restrict__ S2, const unsigned short* __restrict__ H2,
    const int* __restrict__ dst, void* __restrict__ outv, int N,
    const void* __restrict__ W0){
  int tid = threadIdx.x, wv = tid >> 6, lane = tid & 63;
  int isf = detect_f32((const unsigned int*)W0, lane);
  int nodeA = blockIdx.x*8 + wv*2; if (nodeA > N-1) nodeA = N-1;
  int nodeB = nodeA + 1;           if (nodeB > N-1) nodeB = N-1;
  int g = lane >> 3, cbl = (lane & 7)*8;
  int rA0v = dst[(size_t)nodeA*16 + g];
  int rA1v = dst[(size_t)nodeA*16 + 8 + g];
  int rB0v = dst[(size_t)nodeB*16 + g];
  int rB1v = dst[(size_t)nodeB*16 + 8 + g];
  int j = lane & 15;
  int dA = dst[(size_t)nodeA*16 + j];
  int dB = dst[(size_t)nodeB*16 + j];
  // asm queue: 4 score loads, then 4 H2 gathers
  float s0A = gld4(S2, (unsigned)(nodeA*8));
  float s0B = gld4(S2, (unsigned)(nodeB*8));
  float sdA = gld4(S2, (unsigned)(dA*8 + 4));
  float sdB = gld4(S2, (unsigned)(dB*8 + 4));
  f4 lA0 = gld16(H2, (unsigned)(rA0v*128 + cbl*2));
  f4 lA1 = gld16(H2, (unsigned)(rA1v*128 + cbl*2));
  f4 lB0 = gld16(H2, (unsigned)(rB0v*128 + cbl*2));
  f4 lB1 = gld16(H2, (unsigned)(rB1v*128 + cbl*2));
  VMWAIT(4);                           // scores done, gathers flying
  __builtin_amdgcn_sched_barrier(0);
  float eA = lrelu(s0A + sdA);
  float eB = lrelu(s0B + sdB);
  float mA = eA, mB = eB;
  mA = fmaxf(mA, __shfl_xor(mA, 1)); mB = fmaxf(mB, __shfl_xor(mB, 1));
  mA = fmaxf(mA, __shfl_xor(mA, 2)); mB = fmaxf(mB, __shfl_xor(mB, 2));
  mA = fmaxf(mA, __shfl_xor(mA, 4)); mB = fmaxf(mB, __shfl_xor(mB, 4));
  mA = fmaxf(mA, __shfl_xor(mA, 8)); mB = fmaxf(mB, __shfl_xor(mB, 8));
  float pA = __expf(eA - mA), pB = __expf(eB - mB);
  float sA = pA, sB = pB;
  sA += __shfl_xor(sA, 1); sB += __shfl_xor(sB, 1);
  sA += __shfl_xor(sA, 2); sB += __shfl_xor(sB, 2);
  sA += __shfl_xor(sA, 4); sB += __shfl_xor(sB, 4);
  sA += __shfl_xor(sA, 8); sB += __shfl_xor(sB, 8);
  float attA = pA / sA, attB = pB / sB;
  float awA0 = __shfl(attA, g),     awB0 = __shfl(attB, g);
  float awA1 = __shfl(attA, 8 + g), awB1 = __shfl(attB, 8 + g);
  VMWAIT(0);                           // gathers landed
  __builtin_amdgcn_sched_barrier(0);
  bh8 vA0 = __builtin_bit_cast(bh8, lA0);
  bh8 vA1 = __builtin_bit_cast(bh8, lA1);
  bh8 vB0 = __builtin_bit_cast(bh8, lB0);
  bh8 vB1 = __builtin_bit_cast(bh8, lB1);
  float accA[8], accB[8];
  #pragma unroll
  for (int c = 0; c < 8; c++){
    accA[c] = awA0 * b2f((unsigned short)vA0[c]) + awA1 * b2f((unsigned short)vA1[c]);
    accB[c] = awB0 * b2f((unsigned short)vB0[c]) + awB1 * b2f((unsigned short)vB1[c]);
  }
  #pragma unroll
  for (int c = 0; c < 8; c++){
    accA[c] += __shfl_xor(accA[c], 8);  accB[c] += __shfl_xor(accB[c], 8);
    accA[c] += __shfl_xor(accA[c], 16); accB[c] += __shfl_xor(accB[c], 16);
    accA[c] += __shfl_xor(accA[c], 32); accB[c] += __shfl_xor(accB[c], 32);
  }
  if (lane < 8){
    size_t oiA = (size_t)nodeA*64 + cbl;
    size_t oiB = (size_t)nodeB*64 + cbl;
    if (isf){
      float4 a0v, a1v, b0v, b1v;
      a0v.x = elu1(accA[0]); a0v.y = elu1(accA[1]); a0v.z = elu1(accA[2]); a0v.w = elu1(accA[3]);
      a1v.x = elu1(accA[4]); a1v.y = elu1(accA[5]); a1v.z = elu1(accA[6]); a1v.w = elu1(accA[7]);
      b0v.x = elu1(accB[0]); b0v.y = elu1(accB[1]); b0v.z = elu1(accB[2]); b0v.w = elu1(accB[3]);
      b1v.x = elu1(accB[4]); b1v.y = elu1(accB[5]); b1v.z = elu1(accB[6]); b1v.w = elu1(accB[7]);
      *(float4*)((float*)outv + oiA)     = a0v;
      *(float4*)((float*)outv + oiA + 4) = a1v;
      *(float4*)((float*)outv + oiB)     = b0v;
      *(float4*)((float*)outv + oiB + 4) = b1v;
    } else {
      bh8 oA, oB;
      #pragma unroll
      for (int c = 0; c < 8; c++){
        oA[c] = (short)f2b(elu1(accA[c]));
        oB[c] = (short)f2b(elu1(accB[c]));
      }
      *(bh8*)((unsigned short*)outv + oiA) = oA;
      *(bh8*)((unsigned short*)outv + oiB) = oB;
    }
  }
}

extern "C" void kernel_launch(void* const* d_in, const int* in_sizes, int n_in,
                              void* d_out, int out_size, void* d_ws, size_t ws_size,
                              hipStream_t stream){
  const void* X  = d_in[0];
  const int*  ed = (const int*)d_in[1];
  const void* W0 = d_in[2];
  const void* a0 = d_in[3];
  const void* W1 = d_in[4];
  const void* a1 = d_in[5];

  int N = in_sizes[0] / 256;       // 50000
  int E = N * 16;
  const int* dst = ed + E;         // edges[1]; src is structurally e>>4

  char* w = (char*)d_ws;
  size_t off = 0;
  auto alloc = [&](size_t bytes) -> void* {
    void* p = w + off; off += (bytes + 255) & ~(size_t)255; return p;
  };
  unsigned short* Wt1 = (unsigned short*)alloc(272*256*2);
  unsigned short* Wt2 = (unsigned short*)alloc(80*256*2);
  float*          S1  = (float*)alloc((size_t)N*16*4);
  unsigned short* H1  = (unsigned short*)alloc((size_t)N*256*2);
  unsigned short* H2  = (unsigned short*)alloc((size_t)N*64*2);
  float*          S2  = (float*)alloc((size_t)N*2*4);
  (void)ws_size; (void)n_in; (void)out_size;

  int g1 = (N + 79) / 80;
  int gf = (N + 15) / 16;
  int ab = (N + 7) / 8;
  prep_kernel     <<<352,256, 0, stream>>>(W0, a0, W1, a1, Wt1, Wt2);
  gemm1_mfma      <<<g1, 256, 0, stream>>>(X,  Wt1, H1, S1, N, W0);
  fused_agg1_gemm2<<<gf, 256, 0, stream>>>(S1, H1, dst, Wt2, H2, S2, N);
  agg2_kernel     <<<ab, 256, 0, stream>>>(S2, H2, dst, d_out, N, W0);
}